// Round 14
// baseline (426.695 us; speedup 1.0000x reference)
//
#include <hip/hip_runtime.h>
#include <stdint.h>

// B=128, S=400, H=E=512, 4H=2048, 2H=1024, V=50000
using short8 = __attribute__((ext_vector_type(8))) short;
using f32x4  = __attribute__((ext_vector_type(4))) float;

__device__ __forceinline__ unsigned short f2b(float x) {
  union { float f; unsigned u; } v; v.f = x;
  unsigned r = v.u + 0x7FFFu + ((v.u >> 16) & 1u);
  return (unsigned short)(r >> 16);
}

__device__ __forceinline__ float b2f(unsigned short u) {
  union { float f; unsigned v; } x; x.v = ((unsigned)u) << 16; return x.f;
}

__device__ __forceinline__ float fast_tanh(float e) {
  float ex = __expf(e + e);
  return 1.f - 2.f * __builtin_amdgcn_rcpf(ex + 1.f);
}

__device__ __forceinline__ short8 pack8(f32x4 a, f32x4 b) {
  short8 r;
  r[0] = (short)f2b(a[0]); r[1] = (short)f2b(a[1]);
  r[2] = (short)f2b(a[2]); r[3] = (short)f2b(a[3]);
  r[4] = (short)f2b(b[0]); r[5] = (short)f2b(b[1]);
  r[6] = (short)f2b(b[2]); r[7] = (short)f2b(b[3]);
  return r;
}

#define GLDS(src, dst) __builtin_amdgcn_global_load_lds( \
    (const __attribute__((address_space(1))) void*)(src), \
    (__attribute__((address_space(3))) void*)(dst), 16, 0, 0)

// ---------------- K1: pack inputs ----------------
__global__ __launch_bounds__(256) void k_packx(const float* __restrict__ emb,
    const float* __restrict__ pctx, const float* __restrict__ h0,
    unsigned short* __restrict__ xfc, unsigned short* __restrict__ xg)
{
  int b = blockIdx.x;
  for (int c = threadIdx.x; c < 512; c += 256) {
    xfc[(size_t)b * 1024 + c]       = f2b(emb[(size_t)b * 512 + c]);
    xfc[(size_t)b * 1024 + 512 + c] = f2b(pctx[(size_t)b * 512 + c]);
    xg [(size_t)b * 1024 + 512 + c] = f2b(h0[(size_t)b * 512 + c]);
  }
}

// ---------------- K2: fcdec GEMM (8 blocks) + pmass zero (3132 blocks) ----------------
__global__ __launch_bounds__(256) void k_fcdec_pm(const unsigned short* __restrict__ xfc,
    const float* __restrict__ fcW, const float* __restrict__ fcB,
    unsigned short* __restrict__ xg, float* __restrict__ pmass, int pm8)
{
  int tid = threadIdx.x;
  int bid = (int)blockIdx.x;
  if (bid >= 8) {                                // pmass zero
    int i = (bid - 8) * 256 + tid;
    if (i < pm8) {
      float4 z = {0.f, 0.f, 0.f, 0.f};
      float4* p = (float4*)(pmass + (size_t)i * 8);
      p[0] = z; p[1] = z;
    }
    return;
  }
  __shared__ __align__(16) float          Wt[512 * 4];
  __shared__ __align__(16) unsigned short Ct[512 * 8];
  int lane = tid & 63, wave = tid >> 6;
  int l15 = lane & 15, l4 = lane >> 4;
  int v0 = bid * 64;
  int v = v0 + wave * 16 + l15;

  const float* wsrc0; const float* wsrc1;
  const unsigned short* csrc0; const unsigned short* csrc1;
  {
    int s = tid;
    int vr = v0 + ((s >> 7) * 16) + (s & 15);
    wsrc0 = fcW + (size_t)vr * 1024 + ((s >> 4) & 3) * 8 + ((s >> 6) & 1) * 4;
    csrc0 = xfc + (size_t)(s >> 2) * 1024 + (s & 3) * 8;
    s = tid + 256;
    vr = v0 + ((s >> 7) * 16) + (s & 15);
    wsrc1 = fcW + (size_t)vr * 1024 + ((s >> 4) & 3) * 8 + ((s >> 6) & 1) * 4;
    csrc1 = xfc + (size_t)(s >> 2) * 1024 + (s & 3) * 8;
  }

  f32x4 acc[8];
  #pragma unroll
  for (int i = 0; i < 8; ++i) { f32x4 z = {0.f,0.f,0.f,0.f}; acc[i] = z; }

  for (int k0 = 0; k0 < 1024; k0 += 32) {
    __syncthreads();
    GLDS(wsrc0 + k0, Wt + (size_t)tid * 4);
    GLDS(wsrc1 + k0, Wt + (size_t)(tid + 256) * 4);
    GLDS(csrc0 + k0, Ct + (size_t)tid * 8);
    GLDS(csrc1 + k0, Ct + (size_t)(tid + 256) * 8);
    __syncthreads();
    f32x4 f0 = *(const f32x4*)(Wt + (wave * 128 + lane) * 4);
    f32x4 f1 = *(const f32x4*)(Wt + (wave * 128 + 64 + lane) * 4);
    short8 bf = pack8(f0, f1);
    #pragma unroll
    for (int i = 0; i < 8; ++i) {
      short8 af = *(const short8*)(Ct + (i * 64 + l15 * 4 + l4) * 8);
      acc[i] = __builtin_amdgcn_mfma_f32_16x16x32_bf16(af, bf, acc[i], 0, 0, 0);
    }
  }
  float bias = fcB[v];
  #pragma unroll
  for (int i = 0; i < 8; ++i) {
    int rbase = i * 16 + l4 * 4;
    #pragma unroll
    for (int q = 0; q < 4; ++q)
      xg[(size_t)(rbase + q) * 1024 + v] = f2b(acc[i][q] + bias);
  }
}

// ---------------- K3: gates GEMM + fused LSTM (32) + w2t (256) + attnwt (512) ----------------
__global__ __launch_bounds__(256) void k_megaB(const unsigned short* __restrict__ xg,
    const float* __restrict__ Wih, const float* __restrict__ Whh,
    const float* __restrict__ bih, const float* __restrict__ bhh,
    const float* __restrict__ c0, float* __restrict__ hout, float* __restrict__ cout,
    unsigned short* __restrict__ xhc,
    const float* __restrict__ w2, unsigned short* __restrict__ w2t,
    const float* __restrict__ attnW, float* __restrict__ awt)
{
  __shared__ float tile[32][33];
  int tid = threadIdx.x;
  int bid = (int)blockIdx.x;

  if (bid >= 288) {               // attnwt
    int bb = bid - 288;
    int bx = bb & 15, by = bb >> 4;
    int n0 = bx * 32, kk0 = by * 32;
    int tx = tid & 31, ty = tid >> 5;
    #pragma unroll
    for (int i = 0; i < 32; i += 8)
      tile[ty + i][tx] = attnW[(size_t)(kk0 + ty + i) * 512 + n0 + tx];
    __syncthreads();
    #pragma unroll
    for (int i = 0; i < 32; i += 8)
      awt[(size_t)(n0 + ty + i) * 1024 + kk0 + tx] = tile[tx][ty + i];
    return;
  }
  if (bid >= 32) {                // w2t
    int bb = bid - 32;
    int bx = bb & 15, by = bb >> 4;
    int h0 = by * 32, n0 = bx * 32;
    int tx = tid & 31, ty = tid >> 5;
    #pragma unroll
    for (int i = 0; i < 32; i += 8)
      tile[ty + i][tx] = w2[(size_t)(h0 + ty + i) * 512 + n0 + tx];
    __syncthreads();
    #pragma unroll
    for (int i = 0; i < 32; i += 8)
      w2t[(size_t)(n0 + ty + i) * 512 + h0 + tx] = f2b(tile[tx][ty + i]);
    return;
  }

  __shared__ __align__(16) float          Wt[512 * 4];
  __shared__ __align__(16) unsigned short Ct[512 * 8];
  __shared__ float gt[4][128][16];

  int lane = tid & 63, wave = tid >> 6;
  int l15 = lane & 15, l4 = lane >> 4;
  int h0g = bid * 16;

  const float *wA0, *wA1, *wB0, *wB1;
  const unsigned short *csrc0, *csrc1;
  {
    int s = tid;
    size_t off = (size_t)((s >> 7) * 512 + h0g + (s & 15)) * 512
               + ((s >> 4) & 3) * 8 + ((s >> 6) & 1) * 4;
    wA0 = Wih + off; wB0 = Whh + off;
    csrc0 = xg + (size_t)(s >> 2) * 1024 + (s & 3) * 8;
    s = tid + 256;
    off = (size_t)((s >> 7) * 512 + h0g + (s & 15)) * 512
        + ((s >> 4) & 3) * 8 + ((s >> 6) & 1) * 4;
    wA1 = Wih + off; wB1 = Whh + off;
    csrc1 = xg + (size_t)(s >> 2) * 1024 + (s & 3) * 8;
  }

  f32x4 acc[8];
  #pragma unroll
  for (int i = 0; i < 8; ++i) { f32x4 z = {0.f,0.f,0.f,0.f}; acc[i] = z; }

  for (int k0 = 0; k0 < 1024; k0 += 32) {
    __syncthreads();
    if (k0 < 512) {
      GLDS(wA0 + k0, Wt + (size_t)tid * 4);
      GLDS(wA1 + k0, Wt + (size_t)(tid + 256) * 4);
    } else {
      GLDS(wB0 + (k0 - 512), Wt + (size_t)tid * 4);
      GLDS(wB1 + (k0 - 512), Wt + (size_t)(tid + 256) * 4);
    }
    GLDS(csrc0 + k0, Ct + (size_t)tid * 8);
    GLDS(csrc1 + k0, Ct + (size_t)(tid + 256) * 8);
    __syncthreads();
    f32x4 f0 = *(const f32x4*)(Wt + (wave * 128 + lane) * 4);
    f32x4 f1 = *(const f32x4*)(Wt + (wave * 128 + 64 + lane) * 4);
    short8 bf = pack8(f0, f1);
    #pragma unroll
    for (int i = 0; i < 8; ++i) {
      short8 af = *(const short8*)(Ct + (i * 64 + l15 * 4 + l4) * 8);
      acc[i] = __builtin_amdgcn_mfma_f32_16x16x32_bf16(af, bf, acc[i], 0, 0, 0);
    }
  }

  float bias = bih[wave * 512 + h0g + l15] + bhh[wave * 512 + h0g + l15];
  #pragma unroll
  for (int i = 0; i < 8; ++i)
    #pragma unroll
    for (int q = 0; q < 4; ++q)
      gt[wave][i * 16 + l4 * 4 + q][l15] = acc[i][q] + bias;
  __syncthreads();

  #pragma unroll
  for (int j = 0; j < 8; ++j) {
    int e = tid * 8 + j;
    int b = e >> 4, hh = e & 15;
    float gi = gt[0][b][hh], gf = gt[1][b][hh];
    float gg = gt[2][b][hh], go = gt[3][b][hh];
    float si = 1.f / (1.f + expf(-gi));
    float sf = 1.f / (1.f + expf(-gf));
    float so = 1.f / (1.f + expf(-go));
    float cc = sf * c0[(size_t)b * 512 + h0g + hh] + si * tanhf(gg);
    float hv = so * tanhf(cc);
    hout[(size_t)b * 512 + h0g + hh] = hv;
    cout[(size_t)b * 512 + h0g + hh] = cc;
    xhc[(size_t)b * 1024 + h0g + hh] = f2b(hv);
    xhc[(size_t)b * 1024 + 512 + h0g + hh] = f2b(cc);
  }
}

// ---------------- K4: hq GEMM ----------------
__global__ __launch_bounds__(256) void k_hq_mm(const unsigned short* __restrict__ xhc,
    const float* __restrict__ awt, float* __restrict__ hq)
{
  __shared__ __align__(16) float          Wt[512 * 4];
  __shared__ __align__(16) unsigned short Ct[512 * 8];
  int tid = threadIdx.x, lane = tid & 63, wave = tid >> 6;
  int l15 = lane & 15, l4 = lane >> 4;
  int v0 = (int)blockIdx.x * 64;
  int v = v0 + wave * 16 + l15;

  const float* wsrc0; const float* wsrc1;
  const unsigned short* csrc0; const unsigned short* csrc1;
  {
    int s = tid;
    int vr = v0 + ((s >> 7) * 16) + (s & 15);
    wsrc0 = awt + (size_t)vr * 1024 + ((s >> 4) & 3) * 8 + ((s >> 6) & 1) * 4;
    csrc0 = xhc + (size_t)(s >> 2) * 1024 + (s & 3) * 8;
    s = tid + 256;
    vr = v0 + ((s >> 7) * 16) + (s & 15);
    wsrc1 = awt + (size_t)vr * 1024 + ((s >> 4) & 3) * 8 + ((s >> 6) & 1) * 4;
    csrc1 = xhc + (size_t)(s >> 2) * 1024 + (s & 3) * 8;
  }

  f32x4 acc[8];
  #pragma unroll
  for (int i = 0; i < 8; ++i) { f32x4 z = {0.f,0.f,0.f,0.f}; acc[i] = z; }

  for (int k0 = 0; k0 < 1024; k0 += 32) {
    __syncthreads();
    GLDS(wsrc0 + k0, Wt + (size_t)tid * 4);
    GLDS(wsrc1 + k0, Wt + (size_t)(tid + 256) * 4);
    GLDS(csrc0 + k0, Ct + (size_t)tid * 8);
    GLDS(csrc1 + k0, Ct + (size_t)(tid + 256) * 8);
    __syncthreads();
    f32x4 f0 = *(const f32x4*)(Wt + (wave * 128 + lane) * 4);
    f32x4 f1 = *(const f32x4*)(Wt + (wave * 128 + 64 + lane) * 4);
    short8 bf = pack8(f0, f1);
    #pragma unroll
    for (int i = 0; i < 8; ++i) {
      short8 af = *(const short8*)(Ct + (i * 64 + l15 * 4 + l4) * 8);
      acc[i] = __builtin_amdgcn_mfma_f32_16x16x32_bf16(af, bf, acc[i], 0, 0, 0);
    }
  }
  #pragma unroll
  for (int i = 0; i < 8; ++i) {
    int rbase = i * 16 + l4 * 4;
    #pragma unroll
    for (int q = 0; q < 4; ++q)
      hq[(size_t)(rbase + q) * 512 + v] = acc[i][q];
  }
}

// ---------------- K5: energy GEMM — A staged from enc f32 (logits-Wt map, 128 rows) ----------------
// A slot s (16B, 1024 slots): row = (s>>7)*16 + (s&15), col4 = ((s>>4)&3)*8 + ((s>>6)&1)*4
// consume (row = wr*64+ar*16+l15, cols l4*8..+8): f0 slot = (wr*4+ar)*128 + lane, f1 = +64
__global__ __launch_bounds__(256) void k_energy(const float* __restrict__ enc,
    const unsigned short* __restrict__ w2t, const float* __restrict__ hq,
    const float* __restrict__ cov, const float* __restrict__ cw,
    const float* __restrict__ w3, float* __restrict__ att4)
{
  __shared__ __align__(16) float          At[1024 * 4];  // 16 KB (f32)
  __shared__ __align__(16) unsigned short Bt[512 * 8];   // 8 KB (bf16)
  __shared__ float part[2][128];

  int tid = threadIdx.x, lane = tid & 63, wave = tid >> 6;
  int l15 = lane & 15, l4 = lane >> 4;
  int wr = wave >> 1, wc = wave & 1;
  int nt = (int)blockIdx.x & 3, rt = (int)blockIdx.x >> 2;
  int r0 = rt * 128, n0 = nt * 128;

  const float *aF0, *aF1, *aF2, *aF3;
  const unsigned short *bs0, *bs1;
  {
    int s = tid;
    aF0 = enc + (size_t)(r0 + ((s >> 7) << 4) + (s & 15)) * 512
        + ((s >> 4) & 3) * 8 + ((s >> 6) & 1) * 4;
    s = tid + 256;
    aF1 = enc + (size_t)(r0 + ((s >> 7) << 4) + (s & 15)) * 512
        + ((s >> 4) & 3) * 8 + ((s >> 6) & 1) * 4;
    s = tid + 512;
    aF2 = enc + (size_t)(r0 + ((s >> 7) << 4) + (s & 15)) * 512
        + ((s >> 4) & 3) * 8 + ((s >> 6) & 1) * 4;
    s = tid + 768;
    aF3 = enc + (size_t)(r0 + ((s >> 7) << 4) + (s & 15)) * 512
        + ((s >> 4) & 3) * 8 + ((s >> 6) & 1) * 4;
    s = tid;
    bs0 = w2t + (size_t)(n0 + ((s >> 6) << 4) + ((s >> 2) & 15)) * 512 + (s & 3) * 8;
    s = tid + 256;
    bs1 = w2t + (size_t)(n0 + ((s >> 6) << 4) + ((s >> 2) & 15)) * 512 + (s & 3) * 8;
  }

  f32x4 acc[4][4];
  #pragma unroll
  for (int i = 0; i < 4; ++i)
    #pragma unroll
    for (int j = 0; j < 4; ++j) { f32x4 z = {0.f,0.f,0.f,0.f}; acc[i][j] = z; }

  for (int k0 = 0; k0 < 512; k0 += 32) {
    __syncthreads();
    GLDS(aF0 + k0, At + (size_t)tid * 4);
    GLDS(aF1 + k0, At + (size_t)(tid + 256) * 4);
    GLDS(aF2 + k0, At + (size_t)(tid + 512) * 4);
    GLDS(aF3 + k0, At + (size_t)(tid + 768) * 4);
    GLDS(bs0 + k0, Bt + (size_t)tid * 8);
    GLDS(bs1 + k0, Bt + (size_t)(tid + 256) * 8);
    __syncthreads();

    short8 a[4], bfr[4];
    #pragma unroll
    for (int ar = 0; ar < 4; ++ar) {
      int w = wr * 4 + ar;
      f32x4 f0 = *(const f32x4*)(At + (w * 128 + lane) * 4);
      f32x4 f1 = *(const f32x4*)(At + (w * 128 + 64 + lane) * 4);
      a[ar] = pack8(f0, f1);
    }
    #pragma unroll
    for (int bc = 0; bc < 4; ++bc)
      bfr[bc] = *(const short8*)(Bt + ((wc * 4 + bc) * 64 + l15 * 4 + l4) * 8);
    #pragma unroll
    for (int ar = 0; ar < 4; ++ar)
      #pragma unroll
      for (int bc = 0; bc < 4; ++bc)
        acc[ar][bc] = __builtin_amdgcn_mfma_f32_16x16x32_bf16(a[ar], bfr[bc], acc[ar][bc], 0, 0, 0);
  }

  float w3v[4], cwv[4]; int ng[4];
  #pragma unroll
  for (int bc = 0; bc < 4; ++bc) {
    ng[bc] = n0 + wc * 64 + bc * 16 + l15;
    w3v[bc] = w3[ng[bc]]; cwv[bc] = cw[ng[bc]];
  }
  #pragma unroll
  for (int ar = 0; ar < 4; ++ar) {
    #pragma unroll
    for (int q = 0; q < 4; ++q) {
      int bb = wr * 64 + ar * 16 + l4 * 4 + q;
      float cv = cov[bb * 400 + rt];
      const float* hqb = hq + (size_t)bb * 512;
      float sum = 0.f;
      #pragma unroll
      for (int bc = 0; bc < 4; ++bc) {
        float e = acc[ar][bc][q] + hqb[ng[bc]] + cv * cwv[bc];
        sum += fast_tanh(e) * w3v[bc];
      }
      sum += __shfl_xor(sum, 1, 64);
      sum += __shfl_xor(sum, 2, 64);
      sum += __shfl_xor(sum, 4, 64);
      sum += __shfl_xor(sum, 8, 64);
      if (l15 == 0) part[wc][bb] = sum;
    }
  }
  __syncthreads();
  if (tid < 128)
    att4[(size_t)nt * 51200 + tid * 400 + rt] = part[0][tid] + part[1][tid];
}

// ---------------- K6: fused softmax + context + comb + pointer prob ----------------
__global__ __launch_bounds__(256) void k_softctx(const float* __restrict__ att4,
    const float* __restrict__ mask, const float* __restrict__ enc,
    const float* __restrict__ hn, const float* __restrict__ emb,
    const float* __restrict__ ptrW, const float* __restrict__ ptrB,
    float* __restrict__ o_attn, unsigned short* __restrict__ comb,
    float* __restrict__ probptr)
{
  __shared__ float aw[400];
  __shared__ float red[256];
  int b = blockIdx.x, t = threadIdx.x;
  int s1 = t + 256;

  float a0, a1 = -1e30f;
  {
    float raw = att4[b*400 + t] + att4[51200 + b*400 + t]
              + att4[102400 + b*400 + t] + att4[153600 + b*400 + t];
    float m = mask[b*400 + t];
    a0 = m * raw - (1.f - m) * 1e20f;
  }
  if (s1 < 400) {
    float raw = att4[b*400 + s1] + att4[51200 + b*400 + s1]
              + att4[102400 + b*400 + s1] + att4[153600 + b*400 + s1];
    float m = mask[b*400 + s1];
    a1 = m * raw - (1.f - m) * 1e20f;
  }
  red[t] = fmaxf(a0, a1); __syncthreads();
  for (int off = 128; off; off >>= 1) { if (t < off) red[t] = fmaxf(red[t], red[t + off]); __syncthreads(); }
  float mx = red[0]; __syncthreads();
  float e0 = expf(a0 - mx);
  float e1 = (s1 < 400) ? expf(a1 - mx) : 0.f;
  red[t] = e0 + e1; __syncthreads();
  for (int off = 128; off; off >>= 1) { if (t < off) red[t] += red[t + off]; __syncthreads(); }
  float inv = 1.f / red[0];
  float w0 = e0 * inv;
  aw[t] = w0; o_attn[b*400 + t] = w0;
  if (s1 < 400) { float w1 = e1 * inv; aw[s1] = w1; o_attn[b*400 + s1] = w1; }
  __syncthreads();

  int h2 = t * 2;
  float cx = 0.f, cy = 0.f;
  const float* eb = enc + (size_t)b * 512 + h2;
  for (int s = 0; s < 400; ++s) {
    float2 v = *(const float2*)(eb + (size_t)s * 65536);
    float w = aw[s];
    cx += v.x * w; cy += v.y * w;
  }
  float2 hv = *(const float2*)(hn + (size_t)b * 512 + h2);
  float2 ev = *(const float2*)(emb + (size_t)b * 512 + h2);
  comb[(size_t)b*1024 + h2]       = f2b(hv.x);
  comb[(size_t)b*1024 + h2 + 1]   = f2b(hv.y);
  comb[(size_t)b*1024 + 512 + h2]     = f2b(cx);
  comb[(size_t)b*1024 + 512 + h2 + 1] = f2b(cy);
  float pacc = hv.x * (ptrW[h2] + ptrW[1536 + h2])
             + hv.y * (ptrW[h2 + 1] + ptrW[1537 + h2])
             + cx * ptrW[512 + h2] + cy * ptrW[513 + h2]
             + ev.x * ptrW[1024 + h2] + ev.y * ptrW[1025 + h2];
  red[t] = pacc; __syncthreads();
  for (int off = 128; off; off >>= 1) { if (t < off) red[t] += red[t + off]; __syncthreads(); }
  if (t == 0) probptr[b] = 1.f / (1.f + expf(-(red[0] + ptrB[0])));
}

// ---------------- K7: logits GEMM (bf16 out, BK=64 double sub-phase) + scatter ----------------
__global__ __launch_bounds__(256) void k_logits(const unsigned short* __restrict__ comb,
    const float* __restrict__ outW, unsigned short* __restrict__ logitsh, int V,
    const int* __restrict__ widx, const float* __restrict__ attn,
    const float* __restrict__ pp, float* __restrict__ pmass, int ext)
{
  int tid = threadIdx.x;
  int bid = (int)blockIdx.x;
  int nlb = (V + 63) >> 6;
  if (bid >= nlb) {                      // scatter ptr mass into pmass
    int i = (bid - nlb) * 256 + tid;
    if (i < 128 * 400) {
      int b = i / 400;
      atomicAdd(&pmass[(size_t)b * ext + widx[i]], pp[b] * attn[i]);
    }
    return;
  }

  __shared__ __align__(16) float          Wt[1024 * 4];  // 16 KB (two 32-K sub-tiles)
  __shared__ __align__(16) unsigned short Ct[1024 * 8];  // 16 KB

  int lane = tid & 63, wave = tid >> 6;
  int l15 = lane & 15, l4 = lane >> 4;
  int v0 = bid * 64;
  int v = v0 + wave * 16 + l15;

  const float* wsrc0; const float* wsrc1;
  const unsigned short* csrc0; const unsigned short* csrc1;
  {
    int s = tid;
    int vr = v0 + ((s >> 7) * 16) + (s & 15); if (vr >= V) vr = V - 1;
    wsrc0 = outW + (size_t)vr * 1024 + ((s >> 4) & 3) * 8 + ((s >> 6) & 1) * 4;
    csrc0 = comb + (size_t)(s >> 2) * 1024 + (s & 3) * 8;
    s = tid + 256;
    vr = v0 + ((s >> 7) * 16) + (s & 15); if (vr >= V) vr = V - 1;
    wsrc1 = outW + (size_t)vr * 1024 + ((s >> 4) & 3) * 8 + ((s >> 6) & 1) * 4;
    csrc1 = comb + (size_t)(s >> 2) * 1024 + (s & 3) * 8;
  }

  f32x4 acc[8];
  #pragma unroll
  for (int i = 0; i < 8; ++i) { f32x4 z = {0.f,0.f,0.f,0.f}; acc[i] = z; }

  for (int k0 = 0; k0 < 1024; k0 += 64) {
    __syncthreads();
    GLDS(wsrc0 + k0, Wt + (size_t)tid * 4);
    GLDS(wsrc1 + k0, Wt + (size_t)(tid + 256) * 4);
    GLDS(wsrc0 + k0 + 32, Wt + (size_t)(tid + 512) * 4);
    GLDS(wsrc1 + k0 + 32, Wt + (size_t)(tid + 768) * 4);
    GLDS(csrc0 + k0, Ct + (size_t)tid * 8);
    GLDS(csrc1 + k0, Ct + (size_t)(tid + 256) * 8);
    GLDS(csrc0 + k0 + 32, Ct + (size_t)(tid + 512) * 8);
    GLDS(csrc1 + k0 + 32, Ct + (size_t)(tid + 768) * 8);
    __syncthreads();

    {   // sub-phase A (k0)
      f32x4 f0 = *(const f32x4*)(Wt + (wave * 128 + lane) * 4);
      f32x4 f1 = *(const f32x4*)(Wt + (wave * 128 + 64 + lane) * 4);
      short8 bf = pack8(f0, f1);
      #pragma unroll
      for (int i = 0; i < 8; ++i) {
        short8 af = *(const short8*)(Ct + (i * 64 + l15 * 4 + l4) * 8);
        acc[i] = __builtin_amdgcn_mfma_f32_16x16x32_bf16(af, bf, acc[i], 0, 0, 0);
      }
    }
    {   // sub-phase B (k0+32)
      f32x4 f0 = *(const f32x4*)(Wt + (512 + wave * 128 + lane) * 4);
      f32x4 f1 = *(const f32x4*)(Wt + (512 + wave * 128 + 64 + lane) * 4);
      short8 bf = pack8(f0, f1);
      #pragma unroll
      for (int i = 0; i < 8; ++i) {
        short8 af = *(const short8*)(Ct + ((512 + i * 64 + l15 * 4 + l4)) * 8);
        acc[i] = __builtin_amdgcn_mfma_f32_16x16x32_bf16(af, bf, acc[i], 0, 0, 0);
      }
    }
  }

  if (v < V) {
    #pragma unroll
    for (int i = 0; i < 8; ++i) {
      int rbase = i * 16 + l4 * 4;
      #pragma unroll
      for (int q = 0; q < 4; ++q)
        logitsh[(size_t)(rbase + q) * V + v] = f2b(acc[i][q]);
    }
  }
}

// ---------------- K8: per-row max + sum(exp) over bf16 logits ----------------
__global__ __launch_bounds__(256) void k_rowstat(const unsigned short* __restrict__ logitsh,
    float* __restrict__ rmax, float* __restrict__ rsum, int V)
{
  __shared__ float rm[256], rs[256];
  int b = blockIdx.x, t = threadIdx.x;
  float m = -1e30f, s = 0.f;
  for (int v = t; v < V; v += 256) {
    float x = b2f(logitsh[(size_t)b * V + v]);
    if (x > m) { s = s * expf(m - x) + 1.f; m = x; }
    else s += expf(x - m);
  }
  rm[t] = m; rs[t] = s; __syncthreads();
  for (int off = 128; off; off >>= 1) {
    if (t < off) {
      float m1 = rm[t], s1 = rs[t], m2 = rm[t + off], s2 = rs[t + off];
      float M = fmaxf(m1, m2);
      rm[t] = M; rs[t] = s1 * expf(m1 - M) + s2 * expf(m2 - M);
    }
    __syncthreads();
  }
  if (t == 0) { rmax[b] = rm[0]; rsum[b] = rs[0]; }
}

// ---------------- K9: fused probs + ptr-mass + log ----------------
__global__ void k_probs_log(const unsigned short* __restrict__ logitsh,
    const float* __restrict__ rmax, const float* __restrict__ rsum,
    const float* __restrict__ probptr, const float* __restrict__ pmass,
    float* __restrict__ outp, int V, int ext)
{
  int b = blockIdx.y;
  int v = (int)blockIdx.x * 256 + threadIdx.x;
  if (v >= ext) return;
  float val = pmass[(size_t)b * ext + v];
  if (v < V) {
    float pg = 1.f - probptr[b];
    val += pg * expf(b2f(logitsh[(size_t)b * V + v]) - rmax[b]) / rsum[b];
  }
  outp[(size_t)b * ext + v] = logf(val + 1e-31f);
}

// ---------------- host ----------------
extern "C" void kernel_launch(void* const* d_in, const int* in_sizes, int n_in,
                              void* d_out, int out_size, void* d_ws, size_t ws_size,
                              hipStream_t stream) {
  const float* emb   = (const float*)d_in[0];
  const float* h0    = (const float*)d_in[1];
  const float* c0    = (const float*)d_in[2];
  const float* enc   = (const float*)d_in[3];
  const float* cov   = (const float*)d_in[4];
  const float* mask  = (const float*)d_in[5];
  const int*   widx  = (const int*)d_in[6];
  const float* pctx  = (const float*)d_in[7];
  const float* fcW   = (const float*)d_in[9];
  const float* fcB   = (const float*)d_in[10];
  const float* Wih   = (const float*)d_in[11];
  const float* Whh   = (const float*)d_in[12];
  const float* bih   = (const float*)d_in[13];
  const float* bhh   = (const float*)d_in[14];
  const float* attnW = (const float*)d_in[15];
  const float* W2    = (const float*)d_in[16];
  const float* W3    = (const float*)d_in[17];
  const float* cw    = (const float*)d_in[18];
  const float* ptrW  = (const float*)d_in[19];
  const float* ptrB  = (const float*)d_in[20];
  const float* outW  = (const float*)d_in[21];

  const int V   = in_sizes[21] / 1024;                        // 50000
  const int ext = (out_size - 128 * (1024 + 400 + 1)) / 128;  // 50100
  const int pm8 = (128 * ext) / 8;                            // 801,600

  // ws layout (floats). [0, 3.2M) aliased by logitsh (hq/att4/awt/xfc all
  // dead before k_logits writes). pmass persists from launch 2 to the end.
  float* F       = (float*)d_ws;
  unsigned short* logitsh = (unsigned short*)F;   // 6.4M ushorts = 3.2M f
  float* hq      = F;                       // 65536  (dead after k_energy)
  float* att4    = F + 65536;               // 204800 (dead after k_softctx)
  float* awt     = F + 270336;              // 524288 (dead after k_hq_mm)
  unsigned short* xfc = (unsigned short*)(F + 794624);   // 65536 f (dead after k_fcdec_pm)
  float* rmax    = F + 6400000;             // 128
  float* rsum    = F + 6400128;             // 128
  unsigned short* w2t  = (unsigned short*)(F + 6400256); // 131072 f
  unsigned short* comb = (unsigned short*)(F + 6531328); // 65536 f
  unsigned short* xg   = (unsigned short*)(F + 6596864); // 65536 f
  unsigned short* xhc  = (unsigned short*)(F + 6662400); // 65536 f
  float* pmass   = F + 6727936;             // 6,412,800 f -> end 13.14M f = 52.6 MB

  float* outp    = (float*)d_out;
  float* o_probs = outp;
  float* o_h     = outp + (size_t)128 * ext;
  float* o_c     = o_h + 65536;
  float* o_attn  = o_c + 65536;
  float* o_pp    = o_attn + 51200;

  const int pmBlocks = (pm8 + 255) / 256;   // 3132
  const int nlb = (V + 63) / 64;            // 782

  k_packx     <<<128, 256, 0, stream>>>(emb, pctx, h0, xfc, xg);
  k_fcdec_pm  <<<8 + pmBlocks, 256, 0, stream>>>(xfc, fcW, fcB, xg, pmass, pm8);
  k_megaB     <<<800, 256, 0, stream>>>(xg, Wih, Whh, bih, bhh, c0, o_h, o_c, xhc,
                                        W2, w2t, attnW, awt);
  k_hq_mm     <<<8, 256, 0, stream>>>(xhc, awt, hq);
  k_energy    <<<1600, 256, 0, stream>>>(enc, w2t, hq, cov, cw, W3, att4);
  k_softctx   <<<128, 256, 0, stream>>>(att4, mask, enc, o_h, emb, ptrW, ptrB,
                                        o_attn, comb, o_pp);
  k_logits    <<<nlb + 200, 256, 0, stream>>>(comb, outW, logitsh, V,
                                        widx, o_attn, o_pp, pmass, ext);
  k_rowstat   <<<128, 256, 0, stream>>>(logitsh, rmax, rsum, V);
  dim3 gp((ext + 255) / 256, 128);
  k_probs_log <<<gp, 256, 0, stream>>>(logitsh, rmax, rsum, o_pp, pmass,
                                       o_probs, V, ext);
}

// Round 15
// 381.462 us; speedup vs baseline: 1.1186x; 1.1186x over previous
//
#include <hip/hip_runtime.h>
#include <stdint.h>

// B=128, S=400, H=E=512, 4H=2048, 2H=1024, V=50000
using short8 = __attribute__((ext_vector_type(8))) short;
using f32x4  = __attribute__((ext_vector_type(4))) float;

__device__ __forceinline__ unsigned short f2b(float x) {
  union { float f; unsigned u; } v; v.f = x;
  unsigned r = v.u + 0x7FFFu + ((v.u >> 16) & 1u);
  return (unsigned short)(r >> 16);
}

__device__ __forceinline__ float b2f(unsigned short u) {
  union { float f; unsigned v; } x; x.v = ((unsigned)u) << 16; return x.f;
}

__device__ __forceinline__ float fast_tanh(float e) {
  float ex = __expf(e + e);
  return 1.f - 2.f * __builtin_amdgcn_rcpf(ex + 1.f);
}

__device__ __forceinline__ short8 pack8(f32x4 a, f32x4 b) {
  short8 r;
  r[0] = (short)f2b(a[0]); r[1] = (short)f2b(a[1]);
  r[2] = (short)f2b(a[2]); r[3] = (short)f2b(a[3]);
  r[4] = (short)f2b(b[0]); r[5] = (short)f2b(b[1]);
  r[6] = (short)f2b(b[2]); r[7] = (short)f2b(b[3]);
  return r;
}

#define GLDS(src, dst) __builtin_amdgcn_global_load_lds( \
    (const __attribute__((address_space(1))) void*)(src), \
    (__attribute__((address_space(3))) void*)(dst), 16, 0, 0)

// ---------------- K1: pack inputs ----------------
__global__ __launch_bounds__(256) void k_packx(const float* __restrict__ emb,
    const float* __restrict__ pctx, const float* __restrict__ h0,
    unsigned short* __restrict__ xfc, unsigned short* __restrict__ xg)
{
  int b = blockIdx.x;
  for (int c = threadIdx.x; c < 512; c += 256) {
    xfc[(size_t)b * 1024 + c]       = f2b(emb[(size_t)b * 512 + c]);
    xfc[(size_t)b * 1024 + 512 + c] = f2b(pctx[(size_t)b * 512 + c]);
    xg [(size_t)b * 1024 + 512 + c] = f2b(h0[(size_t)b * 512 + c]);
  }
}

// ---------------- K2: fcdec GEMM (8) + enc->bf16 (12800) + pmass zero (3132) ----------------
__global__ __launch_bounds__(256) void k_fcdec_enc(const unsigned short* __restrict__ xfc,
    const float* __restrict__ fcW, const float* __restrict__ fcB,
    unsigned short* __restrict__ xg,
    const float* __restrict__ enc, unsigned short* __restrict__ encb, int n8,
    float* __restrict__ pmass, int pm8)
{
  int tid = threadIdx.x;
  int bid = (int)blockIdx.x;
  if (bid >= 8 + ((n8 + 255) >> 8)) {           // pmass zero
    int i = (bid - 8 - ((n8 + 255) >> 8)) * 256 + tid;
    if (i < pm8) {
      float4 z = {0.f, 0.f, 0.f, 0.f};
      float4* p = (float4*)(pmass + (size_t)i * 8);
      p[0] = z; p[1] = z;
    }
    return;
  }
  if (bid >= 8) {                                // enc f32 -> bf16
    int i = (bid - 8) * 256 + tid;
    if (i < n8) {
      const float4* p = (const float4*)(enc + (size_t)i * 8);
      float4 f0 = p[0], f1 = p[1];
      short8 v;
      v[0] = (short)f2b(f0.x); v[1] = (short)f2b(f0.y);
      v[2] = (short)f2b(f0.z); v[3] = (short)f2b(f0.w);
      v[4] = (short)f2b(f1.x); v[5] = (short)f2b(f1.y);
      v[6] = (short)f2b(f1.z); v[7] = (short)f2b(f1.w);
      *(short8*)(encb + (size_t)i * 8) = v;
    }
    return;
  }
  // fcdec GEMM (proven template)
  __shared__ __align__(16) float          Wt[512 * 4];
  __shared__ __align__(16) unsigned short Ct[512 * 8];
  int lane = tid & 63, wave = tid >> 6;
  int l15 = lane & 15, l4 = lane >> 4;
  int v0 = bid * 64;
  int v = v0 + wave * 16 + l15;

  const float* wsrc0; const float* wsrc1;
  const unsigned short* csrc0; const unsigned short* csrc1;
  {
    int s = tid;
    int vr = v0 + ((s >> 7) * 16) + (s & 15);
    wsrc0 = fcW + (size_t)vr * 1024 + ((s >> 4) & 3) * 8 + ((s >> 6) & 1) * 4;
    csrc0 = xfc + (size_t)(s >> 2) * 1024 + (s & 3) * 8;
    s = tid + 256;
    vr = v0 + ((s >> 7) * 16) + (s & 15);
    wsrc1 = fcW + (size_t)vr * 1024 + ((s >> 4) & 3) * 8 + ((s >> 6) & 1) * 4;
    csrc1 = xfc + (size_t)(s >> 2) * 1024 + (s & 3) * 8;
  }

  f32x4 acc[8];
  #pragma unroll
  for (int i = 0; i < 8; ++i) { f32x4 z = {0.f,0.f,0.f,0.f}; acc[i] = z; }

  for (int k0 = 0; k0 < 1024; k0 += 32) {
    __syncthreads();
    GLDS(wsrc0 + k0, Wt + (size_t)tid * 4);
    GLDS(wsrc1 + k0, Wt + (size_t)(tid + 256) * 4);
    GLDS(csrc0 + k0, Ct + (size_t)tid * 8);
    GLDS(csrc1 + k0, Ct + (size_t)(tid + 256) * 8);
    __syncthreads();
    f32x4 f0 = *(const f32x4*)(Wt + (wave * 128 + lane) * 4);
    f32x4 f1 = *(const f32x4*)(Wt + (wave * 128 + 64 + lane) * 4);
    short8 bf = pack8(f0, f1);
    #pragma unroll
    for (int i = 0; i < 8; ++i) {
      short8 af = *(const short8*)(Ct + (i * 64 + l15 * 4 + l4) * 8);
      acc[i] = __builtin_amdgcn_mfma_f32_16x16x32_bf16(af, bf, acc[i], 0, 0, 0);
    }
  }
  float bias = fcB[v];
  #pragma unroll
  for (int i = 0; i < 8; ++i) {
    int rbase = i * 16 + l4 * 4;
    #pragma unroll
    for (int q = 0; q < 4; ++q)
      xg[(size_t)(rbase + q) * 1024 + v] = f2b(acc[i][q] + bias);
  }
}

// ---------------- K3: gates GEMM + fused LSTM (32) + w2t (256) + attnwt (512) ----------------
__global__ __launch_bounds__(256) void k_megaB(const unsigned short* __restrict__ xg,
    const float* __restrict__ Wih, const float* __restrict__ Whh,
    const float* __restrict__ bih, const float* __restrict__ bhh,
    const float* __restrict__ c0, float* __restrict__ hout, float* __restrict__ cout,
    unsigned short* __restrict__ xhc,
    const float* __restrict__ w2, unsigned short* __restrict__ w2t,
    const float* __restrict__ attnW, float* __restrict__ awt)
{
  __shared__ float tile[32][33];
  int tid = threadIdx.x;
  int bid = (int)blockIdx.x;

  if (bid >= 288) {               // attnwt
    int bb = bid - 288;
    int bx = bb & 15, by = bb >> 4;
    int n0 = bx * 32, kk0 = by * 32;
    int tx = tid & 31, ty = tid >> 5;
    #pragma unroll
    for (int i = 0; i < 32; i += 8)
      tile[ty + i][tx] = attnW[(size_t)(kk0 + ty + i) * 512 + n0 + tx];
    __syncthreads();
    #pragma unroll
    for (int i = 0; i < 32; i += 8)
      awt[(size_t)(n0 + ty + i) * 1024 + kk0 + tx] = tile[tx][ty + i];
    return;
  }
  if (bid >= 32) {                // w2t
    int bb = bid - 32;
    int bx = bb & 15, by = bb >> 4;
    int h0 = by * 32, n0 = bx * 32;
    int tx = tid & 31, ty = tid >> 5;
    #pragma unroll
    for (int i = 0; i < 32; i += 8)
      tile[ty + i][tx] = w2[(size_t)(h0 + ty + i) * 512 + n0 + tx];
    __syncthreads();
    #pragma unroll
    for (int i = 0; i < 32; i += 8)
      w2t[(size_t)(n0 + ty + i) * 512 + h0 + tx] = f2b(tile[tx][ty + i]);
    return;
  }

  __shared__ __align__(16) float          Wt[512 * 4];
  __shared__ __align__(16) unsigned short Ct[512 * 8];
  __shared__ float gt[4][128][16];

  int lane = tid & 63, wave = tid >> 6;
  int l15 = lane & 15, l4 = lane >> 4;
  int h0g = bid * 16;

  const float *wA0, *wA1, *wB0, *wB1;
  const unsigned short *csrc0, *csrc1;
  {
    int s = tid;
    size_t off = (size_t)((s >> 7) * 512 + h0g + (s & 15)) * 512
               + ((s >> 4) & 3) * 8 + ((s >> 6) & 1) * 4;
    wA0 = Wih + off; wB0 = Whh + off;
    csrc0 = xg + (size_t)(s >> 2) * 1024 + (s & 3) * 8;
    s = tid + 256;
    off = (size_t)((s >> 7) * 512 + h0g + (s & 15)) * 512
        + ((s >> 4) & 3) * 8 + ((s >> 6) & 1) * 4;
    wA1 = Wih + off; wB1 = Whh + off;
    csrc1 = xg + (size_t)(s >> 2) * 1024 + (s & 3) * 8;
  }

  f32x4 acc[8];
  #pragma unroll
  for (int i = 0; i < 8; ++i) { f32x4 z = {0.f,0.f,0.f,0.f}; acc[i] = z; }

  for (int k0 = 0; k0 < 1024; k0 += 32) {
    __syncthreads();
    if (k0 < 512) {
      GLDS(wA0 + k0, Wt + (size_t)tid * 4);
      GLDS(wA1 + k0, Wt + (size_t)(tid + 256) * 4);
    } else {
      GLDS(wB0 + (k0 - 512), Wt + (size_t)tid * 4);
      GLDS(wB1 + (k0 - 512), Wt + (size_t)(tid + 256) * 4);
    }
    GLDS(csrc0 + k0, Ct + (size_t)tid * 8);
    GLDS(csrc1 + k0, Ct + (size_t)(tid + 256) * 8);
    __syncthreads();
    f32x4 f0 = *(const f32x4*)(Wt + (wave * 128 + lane) * 4);
    f32x4 f1 = *(const f32x4*)(Wt + (wave * 128 + 64 + lane) * 4);
    short8 bf = pack8(f0, f1);
    #pragma unroll
    for (int i = 0; i < 8; ++i) {
      short8 af = *(const short8*)(Ct + (i * 64 + l15 * 4 + l4) * 8);
      acc[i] = __builtin_amdgcn_mfma_f32_16x16x32_bf16(af, bf, acc[i], 0, 0, 0);
    }
  }

  float bias = bih[wave * 512 + h0g + l15] + bhh[wave * 512 + h0g + l15];
  #pragma unroll
  for (int i = 0; i < 8; ++i)
    #pragma unroll
    for (int q = 0; q < 4; ++q)
      gt[wave][i * 16 + l4 * 4 + q][l15] = acc[i][q] + bias;
  __syncthreads();

  #pragma unroll
  for (int j = 0; j < 8; ++j) {
    int e = tid * 8 + j;
    int b = e >> 4, hh = e & 15;
    float gi = gt[0][b][hh], gf = gt[1][b][hh];
    float gg = gt[2][b][hh], go = gt[3][b][hh];
    float si = 1.f / (1.f + expf(-gi));
    float sf = 1.f / (1.f + expf(-gf));
    float so = 1.f / (1.f + expf(-go));
    float cc = sf * c0[(size_t)b * 512 + h0g + hh] + si * tanhf(gg);
    float hv = so * tanhf(cc);
    hout[(size_t)b * 512 + h0g + hh] = hv;
    cout[(size_t)b * 512 + h0g + hh] = cc;
    xhc[(size_t)b * 1024 + h0g + hh] = f2b(hv);
    xhc[(size_t)b * 1024 + 512 + h0g + hh] = f2b(cc);
  }
}

// ---------------- K4: hq GEMM ----------------
__global__ __launch_bounds__(256) void k_hq_mm(const unsigned short* __restrict__ xhc,
    const float* __restrict__ awt, float* __restrict__ hq)
{
  __shared__ __align__(16) float          Wt[512 * 4];
  __shared__ __align__(16) unsigned short Ct[512 * 8];
  int tid = threadIdx.x, lane = tid & 63, wave = tid >> 6;
  int l15 = lane & 15, l4 = lane >> 4;
  int v0 = (int)blockIdx.x * 64;
  int v = v0 + wave * 16 + l15;

  const float* wsrc0; const float* wsrc1;
  const unsigned short* csrc0; const unsigned short* csrc1;
  {
    int s = tid;
    int vr = v0 + ((s >> 7) * 16) + (s & 15);
    wsrc0 = awt + (size_t)vr * 1024 + ((s >> 4) & 3) * 8 + ((s >> 6) & 1) * 4;
    csrc0 = xhc + (size_t)(s >> 2) * 1024 + (s & 3) * 8;
    s = tid + 256;
    vr = v0 + ((s >> 7) * 16) + (s & 15);
    wsrc1 = awt + (size_t)vr * 1024 + ((s >> 4) & 3) * 8 + ((s >> 6) & 1) * 4;
    csrc1 = xhc + (size_t)(s >> 2) * 1024 + (s & 3) * 8;
  }

  f32x4 acc[8];
  #pragma unroll
  for (int i = 0; i < 8; ++i) { f32x4 z = {0.f,0.f,0.f,0.f}; acc[i] = z; }

  for (int k0 = 0; k0 < 1024; k0 += 32) {
    __syncthreads();
    GLDS(wsrc0 + k0, Wt + (size_t)tid * 4);
    GLDS(wsrc1 + k0, Wt + (size_t)(tid + 256) * 4);
    GLDS(csrc0 + k0, Ct + (size_t)tid * 8);
    GLDS(csrc1 + k0, Ct + (size_t)(tid + 256) * 8);
    __syncthreads();
    f32x4 f0 = *(const f32x4*)(Wt + (wave * 128 + lane) * 4);
    f32x4 f1 = *(const f32x4*)(Wt + (wave * 128 + 64 + lane) * 4);
    short8 bf = pack8(f0, f1);
    #pragma unroll
    for (int i = 0; i < 8; ++i) {
      short8 af = *(const short8*)(Ct + (i * 64 + l15 * 4 + l4) * 8);
      acc[i] = __builtin_amdgcn_mfma_f32_16x16x32_bf16(af, bf, acc[i], 0, 0, 0);
    }
  }
  #pragma unroll
  for (int i = 0; i < 8; ++i) {
    int rbase = i * 16 + l4 * 4;
    #pragma unroll
    for (int q = 0; q < 4; ++q)
      hq[(size_t)(rbase + q) * 512 + v] = acc[i][q];
  }
}

// ---------------- K5: energy GEMM (R13-proven: encb bf16 A/B, GLDS, fused epilogue) ----------------
__global__ __launch_bounds__(256) void k_energy(const unsigned short* __restrict__ encb,
    const unsigned short* __restrict__ w2t, const float* __restrict__ hq,
    const float* __restrict__ cov, const float* __restrict__ cw,
    const float* __restrict__ w3, float* __restrict__ att4)
{
  __shared__ __align__(16) unsigned short At[512 * 8];
  __shared__ __align__(16) unsigned short Bt[512 * 8];
  __shared__ float part[2][128];

  int tid = threadIdx.x, lane = tid & 63, wave = tid >> 6;
  int l15 = lane & 15, l4 = lane >> 4;
  int wr = wave >> 1, wc = wave & 1;
  int nt = (int)blockIdx.x & 3, rt = (int)blockIdx.x >> 2;
  int r0 = rt * 128, n0 = nt * 128;

  const unsigned short *as0, *as1, *bs0, *bs1;
  {
    int s = tid;
    int row = ((s >> 6) << 4) + ((s >> 2) & 15), kg = s & 3;
    as0 = encb + (size_t)(r0 + row) * 512 + kg * 8;
    bs0 = w2t  + (size_t)(n0 + row) * 512 + kg * 8;
    s = tid + 256;
    row = ((s >> 6) << 4) + ((s >> 2) & 15); kg = s & 3;
    as1 = encb + (size_t)(r0 + row) * 512 + kg * 8;
    bs1 = w2t  + (size_t)(n0 + row) * 512 + kg * 8;
  }

  f32x4 acc[4][4];
  #pragma unroll
  for (int i = 0; i < 4; ++i)
    #pragma unroll
    for (int j = 0; j < 4; ++j) { f32x4 z = {0.f,0.f,0.f,0.f}; acc[i][j] = z; }

  for (int k0 = 0; k0 < 512; k0 += 32) {
    __syncthreads();
    GLDS(as0 + k0, At + (size_t)tid * 8);
    GLDS(as1 + k0, At + (size_t)(tid + 256) * 8);
    GLDS(bs0 + k0, Bt + (size_t)tid * 8);
    GLDS(bs1 + k0, Bt + (size_t)(tid + 256) * 8);
    __syncthreads();

    short8 a[4], bfr[4];
    #pragma unroll
    for (int ar = 0; ar < 4; ++ar)
      a[ar] = *(const short8*)(At + ((wr * 4 + ar) * 64 + l15 * 4 + l4) * 8);
    #pragma unroll
    for (int bc = 0; bc < 4; ++bc)
      bfr[bc] = *(const short8*)(Bt + ((wc * 4 + bc) * 64 + l15 * 4 + l4) * 8);
    #pragma unroll
    for (int ar = 0; ar < 4; ++ar)
      #pragma unroll
      for (int bc = 0; bc < 4; ++bc)
        acc[ar][bc] = __builtin_amdgcn_mfma_f32_16x16x32_bf16(a[ar], bfr[bc], acc[ar][bc], 0, 0, 0);
  }

  float w3v[4], cwv[4]; int ng[4];
  #pragma unroll
  for (int bc = 0; bc < 4; ++bc) {
    ng[bc] = n0 + wc * 64 + bc * 16 + l15;
    w3v[bc] = w3[ng[bc]]; cwv[bc] = cw[ng[bc]];
  }
  #pragma unroll
  for (int ar = 0; ar < 4; ++ar) {
    #pragma unroll
    for (int q = 0; q < 4; ++q) {
      int bb = wr * 64 + ar * 16 + l4 * 4 + q;
      float cv = cov[bb * 400 + rt];
      const float* hqb = hq + (size_t)bb * 512;
      float sum = 0.f;
      #pragma unroll
      for (int bc = 0; bc < 4; ++bc) {
        float e = acc[ar][bc][q] + hqb[ng[bc]] + cv * cwv[bc];
        sum += fast_tanh(e) * w3v[bc];
      }
      sum += __shfl_xor(sum, 1, 64);
      sum += __shfl_xor(sum, 2, 64);
      sum += __shfl_xor(sum, 4, 64);
      sum += __shfl_xor(sum, 8, 64);
      if (l15 == 0) part[wc][bb] = sum;
    }
  }
  __syncthreads();
  if (tid < 128)
    att4[(size_t)nt * 51200 + tid * 400 + rt] = part[0][tid] + part[1][tid];
}

// ---------------- K6: fused softmax + context + comb + pointer prob ----------------
__global__ __launch_bounds__(256) void k_softctx(const float* __restrict__ att4,
    const float* __restrict__ mask, const unsigned short* __restrict__ encb,
    const float* __restrict__ hn, const float* __restrict__ emb,
    const float* __restrict__ ptrW, const float* __restrict__ ptrB,
    float* __restrict__ o_attn, unsigned short* __restrict__ comb,
    float* __restrict__ probptr)
{
  __shared__ float aw[400];
  __shared__ float red[256];
  int b = blockIdx.x, t = threadIdx.x;
  int s1 = t + 256;

  float a0, a1 = -1e30f;
  {
    float raw = att4[b*400 + t] + att4[51200 + b*400 + t]
              + att4[102400 + b*400 + t] + att4[153600 + b*400 + t];
    float m = mask[b*400 + t];
    a0 = m * raw - (1.f - m) * 1e20f;
  }
  if (s1 < 400) {
    float raw = att4[b*400 + s1] + att4[51200 + b*400 + s1]
              + att4[102400 + b*400 + s1] + att4[153600 + b*400 + s1];
    float m = mask[b*400 + s1];
    a1 = m * raw - (1.f - m) * 1e20f;
  }
  red[t] = fmaxf(a0, a1); __syncthreads();
  for (int off = 128; off; off >>= 1) { if (t < off) red[t] = fmaxf(red[t], red[t + off]); __syncthreads(); }
  float mx = red[0]; __syncthreads();
  float e0 = expf(a0 - mx);
  float e1 = (s1 < 400) ? expf(a1 - mx) : 0.f;
  red[t] = e0 + e1; __syncthreads();
  for (int off = 128; off; off >>= 1) { if (t < off) red[t] += red[t + off]; __syncthreads(); }
  float inv = 1.f / red[0];
  float w0 = e0 * inv;
  aw[t] = w0; o_attn[b*400 + t] = w0;
  if (s1 < 400) { float w1 = e1 * inv; aw[s1] = w1; o_attn[b*400 + s1] = w1; }
  __syncthreads();

  int h2 = t * 2;
  float cx = 0.f, cy = 0.f;
  const unsigned short* eb = encb + (size_t)b * 512 + h2;
  for (int s = 0; s < 400; ++s) {
    ushort2 v = *(const ushort2*)(eb + (size_t)s * 65536);
    float w = aw[s];
    cx += b2f(v.x) * w; cy += b2f(v.y) * w;
  }
  float2 hv = *(const float2*)(hn + (size_t)b * 512 + h2);
  float2 ev = *(const float2*)(emb + (size_t)b * 512 + h2);
  comb[(size_t)b*1024 + h2]       = f2b(hv.x);
  comb[(size_t)b*1024 + h2 + 1]   = f2b(hv.y);
  comb[(size_t)b*1024 + 512 + h2]     = f2b(cx);
  comb[(size_t)b*1024 + 512 + h2 + 1] = f2b(cy);
  float pacc = hv.x * (ptrW[h2] + ptrW[1536 + h2])
             + hv.y * (ptrW[h2 + 1] + ptrW[1537 + h2])
             + cx * ptrW[512 + h2] + cy * ptrW[513 + h2]
             + ev.x * ptrW[1024 + h2] + ev.y * ptrW[1025 + h2];
  red[t] = pacc; __syncthreads();
  for (int off = 128; off; off >>= 1) { if (t < off) red[t] += red[t + off]; __syncthreads(); }
  if (t == 0) probptr[b] = 1.f / (1.f + expf(-(red[0] + ptrB[0])));
}

// ---------------- K7: logits GEMM (bf16 out, BK=64 double sub-phase) + scatter ----------------
__global__ __launch_bounds__(256) void k_logits(const unsigned short* __restrict__ comb,
    const float* __restrict__ outW, unsigned short* __restrict__ logitsh, int V,
    const int* __restrict__ widx, const float* __restrict__ attn,
    const float* __restrict__ pp, float* __restrict__ pmass, int ext)
{
  int tid = threadIdx.x;
  int bid = (int)blockIdx.x;
  int nlb = (V + 63) >> 6;
  if (bid >= nlb) {                      // scatter ptr mass into pmass
    int i = (bid - nlb) * 256 + tid;
    if (i < 128 * 400) {
      int b = i / 400;
      atomicAdd(&pmass[(size_t)b * ext + widx[i]], pp[b] * attn[i]);
    }
    return;
  }

  __shared__ __align__(16) float          Wt[1024 * 4];  // 16 KB (two 32-K sub-tiles)
  __shared__ __align__(16) unsigned short Ct[1024 * 8];  // 16 KB

  int lane = tid & 63, wave = tid >> 6;
  int l15 = lane & 15, l4 = lane >> 4;
  int v0 = bid * 64;
  int v = v0 + wave * 16 + l15;

  const float* wsrc0; const float* wsrc1;
  const unsigned short* csrc0; const unsigned short* csrc1;
  {
    int s = tid;
    int vr = v0 + ((s >> 7) * 16) + (s & 15); if (vr >= V) vr = V - 1;
    wsrc0 = outW + (size_t)vr * 1024 + ((s >> 4) & 3) * 8 + ((s >> 6) & 1) * 4;
    csrc0 = comb + (size_t)(s >> 2) * 1024 + (s & 3) * 8;
    s = tid + 256;
    vr = v0 + ((s >> 7) * 16) + (s & 15); if (vr >= V) vr = V - 1;
    wsrc1 = outW + (size_t)vr * 1024 + ((s >> 4) & 3) * 8 + ((s >> 6) & 1) * 4;
    csrc1 = comb + (size_t)(s >> 2) * 1024 + (s & 3) * 8;
  }

  f32x4 acc[8];
  #pragma unroll
  for (int i = 0; i < 8; ++i) { f32x4 z = {0.f,0.f,0.f,0.f}; acc[i] = z; }

  for (int k0 = 0; k0 < 1024; k0 += 64) {
    __syncthreads();
    GLDS(wsrc0 + k0, Wt + (size_t)tid * 4);
    GLDS(wsrc1 + k0, Wt + (size_t)(tid + 256) * 4);
    GLDS(wsrc0 + k0 + 32, Wt + (size_t)(tid + 512) * 4);
    GLDS(wsrc1 + k0 + 32, Wt + (size_t)(tid + 768) * 4);
    GLDS(csrc0 + k0, Ct + (size_t)tid * 8);
    GLDS(csrc1 + k0, Ct + (size_t)(tid + 256) * 8);
    GLDS(csrc0 + k0 + 32, Ct + (size_t)(tid + 512) * 8);
    GLDS(csrc1 + k0 + 32, Ct + (size_t)(tid + 768) * 8);
    __syncthreads();

    {   // sub-phase A (k0)
      f32x4 f0 = *(const f32x4*)(Wt + (wave * 128 + lane) * 4);
      f32x4 f1 = *(const f32x4*)(Wt + (wave * 128 + 64 + lane) * 4);
      short8 bf = pack8(f0, f1);
      #pragma unroll
      for (int i = 0; i < 8; ++i) {
        short8 af = *(const short8*)(Ct + (i * 64 + l15 * 4 + l4) * 8);
        acc[i] = __builtin_amdgcn_mfma_f32_16x16x32_bf16(af, bf, acc[i], 0, 0, 0);
      }
    }
    {   // sub-phase B (k0+32)
      f32x4 f0 = *(const f32x4*)(Wt + (512 + wave * 128 + lane) * 4);
      f32x4 f1 = *(const f32x4*)(Wt + (512 + wave * 128 + 64 + lane) * 4);
      short8 bf = pack8(f0, f1);
      #pragma unroll
      for (int i = 0; i < 8; ++i) {
        short8 af = *(const short8*)(Ct + ((512 + i * 64 + l15 * 4 + l4)) * 8);
        acc[i] = __builtin_amdgcn_mfma_f32_16x16x32_bf16(af, bf, acc[i], 0, 0, 0);
      }
    }
  }

  if (v < V) {
    #pragma unroll
    for (int i = 0; i < 8; ++i) {
      int rbase = i * 16 + l4 * 4;
      #pragma unroll
      for (int q = 0; q < 4; ++q)
        logitsh[(size_t)(rbase + q) * V + v] = f2b(acc[i][q]);
    }
  }
}

// ---------------- K8: per-row max + sum(exp) over bf16 logits ----------------
__global__ __launch_bounds__(256) void k_rowstat(const unsigned short* __restrict__ logitsh,
    float* __restrict__ rmax, float* __restrict__ rsum, int V)
{
  __shared__ float rm[256], rs[256];
  int b = blockIdx.x, t = threadIdx.x;
  float m = -1e30f, s = 0.f;
  for (int v = t; v < V; v += 256) {
    float x = b2f(logitsh[(size_t)b * V + v]);
    if (x > m) { s = s * expf(m - x) + 1.f; m = x; }
    else s += expf(x - m);
  }
  rm[t] = m; rs[t] = s; __syncthreads();
  for (int off = 128; off; off >>= 1) {
    if (t < off) {
      float m1 = rm[t], s1 = rs[t], m2 = rm[t + off], s2 = rs[t + off];
      float M = fmaxf(m1, m2);
      rm[t] = M; rs[t] = s1 * expf(m1 - M) + s2 * expf(m2 - M);
    }
    __syncthreads();
  }
  if (t == 0) { rmax[b] = rm[0]; rsum[b] = rs[0]; }
}

// ---------------- K9: fused probs + ptr-mass + log ----------------
__global__ void k_probs_log(const unsigned short* __restrict__ logitsh,
    const float* __restrict__ rmax, const float* __restrict__ rsum,
    const float* __restrict__ probptr, const float* __restrict__ pmass,
    float* __restrict__ outp, int V, int ext)
{
  int b = blockIdx.y;
  int v = (int)blockIdx.x * 256 + threadIdx.x;
  if (v >= ext) return;
  float val = pmass[(size_t)b * ext + v];
  if (v < V) {
    float pg = 1.f - probptr[b];
    val += pg * expf(b2f(logitsh[(size_t)b * V + v]) - rmax[b]) / rsum[b];
  }
  outp[(size_t)b * ext + v] = logf(val + 1e-31f);
}

// ---------------- host ----------------
extern "C" void kernel_launch(void* const* d_in, const int* in_sizes, int n_in,
                              void* d_out, int out_size, void* d_ws, size_t ws_size,
                              hipStream_t stream) {
  const float* emb   = (const float*)d_in[0];
  const float* h0    = (const float*)d_in[1];
  const float* c0    = (const float*)d_in[2];
  const float* enc   = (const float*)d_in[3];
  const float* cov   = (const float*)d_in[4];
  const float* mask  = (const float*)d_in[5];
  const int*   widx  = (const int*)d_in[6];
  const float* pctx  = (const float*)d_in[7];
  const float* fcW   = (const float*)d_in[9];
  const float* fcB   = (const float*)d_in[10];
  const float* Wih   = (const float*)d_in[11];
  const float* Whh   = (const float*)d_in[12];
  const float* bih   = (const float*)d_in[13];
  const float* bhh   = (const float*)d_in[14];
  const float* attnW = (const float*)d_in[15];
  const float* W2    = (const float*)d_in[16];
  const float* W3    = (const float*)d_in[17];
  const float* cw    = (const float*)d_in[18];
  const float* ptrW  = (const float*)d_in[19];
  const float* ptrB  = (const float*)d_in[20];
  const float* outW  = (const float*)d_in[21];

  const int V   = in_sizes[21] / 1024;                        // 50000
  const int ext = (out_size - 128 * (1024 + 400 + 1)) / 128;  // 50100
  const int encN8 = in_sizes[3] / 8;                          // 3,276,800
  const int pm8   = (128 * ext) / 8;                          // 801,600

  // ws layout (floats). [0, 3.2M) aliased by logitsh (hq/att4/awt/xfc all
  // dead before k_logits writes). pmass + encb persist.
  float* F       = (float*)d_ws;
  unsigned short* logitsh = (unsigned short*)F;   // 6.4M ushorts = 3.2M f
  float* hq      = F;                       // 65536  (dead after k_energy)
  float* att4    = F + 65536;               // 204800 (dead after k_softctx)
  float* awt     = F + 270336;              // 524288 (dead after k_hq_mm)
  unsigned short* xfc = (unsigned short*)(F + 794624);   // 65536 f (dead after k_fcdec_enc)
  float* rmax    = F + 6400000;             // 128
  float* rsum    = F + 6400128;             // 128
  unsigned short* w2t  = (unsigned short*)(F + 6400256); // 131072 f
  unsigned short* comb = (unsigned short*)(F + 6531328); // 65536 f
  unsigned short* xg   = (unsigned short*)(F + 6596864); // 65536 f
  unsigned short* xhc  = (unsigned short*)(F + 6662400); // 65536 f
  unsigned short* encb = (unsigned short*)(F + 6727936); // 13,107,200 f
  float* pmass   = F + 19835136;            // 6,412,800 f -> end 26.25M f = 105 MB

  float* outp    = (float*)d_out;
  float* o_probs = outp;
  float* o_h     = outp + (size_t)128 * ext;
  float* o_c     = o_h + 65536;
  float* o_attn  = o_c + 65536;
  float* o_pp    = o_attn + 51200;

  const int encBlocks = (encN8 + 255) / 256;   // 12800
  const int pmBlocks  = (pm8 + 255) / 256;     // 3132
  const int nlb = (V + 63) / 64;               // 782

  k_packx     <<<128, 256, 0, stream>>>(emb, pctx, h0, xfc, xg);
  k_fcdec_enc <<<8 + encBlocks + pmBlocks, 256, 0, stream>>>(xfc, fcW, fcB, xg,
                                        enc, encb, encN8, pmass, pm8);
  k_megaB     <<<800, 256, 0, stream>>>(xg, Wih, Whh, bih, bhh, c0, o_h, o_c, xhc,
                                        W2, w2t, attnW, awt);
  k_hq_mm     <<<8, 256, 0, stream>>>(xhc, awt, hq);
  k_energy    <<<1600, 256, 0, stream>>>(encb, w2t, hq, cov, cw, W3, att4);
  k_softctx   <<<128, 256, 0, stream>>>(att4, mask, encb, o_h, emb, ptrW, ptrB,
                                        o_attn, comb, o_pp);
  k_logits    <<<nlb + 200, 256, 0, stream>>>(comb, outW, logitsh, V,
                                        widx, o_attn, o_pp, pmass, ext);
  k_rowstat   <<<128, 256, 0, stream>>>(logitsh, rmax, rsum, V);
  dim3 gp((ext + 255) / 256, 128);
  k_probs_log <<<gp, 256, 0, stream>>>(logitsh, rmax, rsum, o_pp, pmass,
                                       o_probs, V, ext);
}